// Round 2
// baseline (582.025 us; speedup 1.0000x reference)
//
#include <hip/hip_runtime.h>
#include <hip/hip_bf16.h>
#include <stdint.h>

#define T_SEQ 1024
#define DMODEL 3584
#define KVDIM 512
#define NQH 28
#define NKVH 4
#define NREP 7
#define HD 128
#define NTOT 4608          // DMODEL + 2*KVDIM
#define BATCH 2
#define MROWS 2048         // BATCH * T_SEQ
#define KMASK (-3.3895314e38f)

typedef __attribute__((ext_vector_type(8))) short short8;
typedef __attribute__((ext_vector_type(4))) float f32x4;

__device__ __forceinline__ short8 ld_s8(const __hip_bfloat16* p) {
    return *reinterpret_cast<const short8*>(p);
}

__device__ __forceinline__ f32x4 mfma16(short8 a, short8 b, f32x4 c) {
    return __builtin_amdgcn_mfma_f32_16x16x32_bf16(a, b, c, 0, 0, 0);
}

__device__ __forceinline__ void gload_lds16(const __hip_bfloat16* g, __hip_bfloat16* l) {
    __builtin_amdgcn_global_load_lds(
        (const __attribute__((address_space(1))) unsigned int*)g,
        (__attribute__((address_space(3))) unsigned int*)l,
        16, 0, 0);
}

// ---------------- segment scan: position ids + left pads ----------------
__global__ void scan_kernel(const int* __restrict__ seg, int* __restrict__ pos_ids,
                            int* __restrict__ left_pads) {
    int b = blockIdx.x;
    int t = threadIdx.x;
    __shared__ int cum[T_SEQ];
    __shared__ int lp;
    if (t == 0) lp = 0;
    cum[t] = (seg[b * T_SEQ + t] != 0) ? 1 : 0;
    __syncthreads();
    for (int off = 1; off < T_SEQ; off <<= 1) {
        int add = (t >= off) ? cum[t - off] : 0;
        __syncthreads();
        cum[t] += add;
        __syncthreads();
    }
    pos_ids[b * T_SEQ + t] = cum[t] - 1;
    if (cum[t] == 0) atomicAdd(&lp, 1);
    __syncthreads();
    if (t == 0) left_pads[b] = lp;
}

// ---------------- fp32 -> bf16 elementwise ----------------
__global__ void convert_bf16(const float* __restrict__ x, __hip_bfloat16* __restrict__ xb, int n) {
    int i = (blockIdx.x * blockDim.x + threadIdx.x) * 4;
    if (i >= n) return;
    float4 v = *reinterpret_cast<const float4*>(x + i);
    union { __hip_bfloat16 h[4]; uint2 u; } o;
    o.h[0] = __float2bfloat16(v.x);
    o.h[1] = __float2bfloat16(v.y);
    o.h[2] = __float2bfloat16(v.z);
    o.h[3] = __float2bfloat16(v.w);
    *reinterpret_cast<uint2*>(xb + i) = o.u;
}

// ---------------- transpose + convert: W (KxN fp32) -> WT (NxK bf16) ----------------
__global__ void transpose_convert(const float* __restrict__ W, __hip_bfloat16* __restrict__ WT,
                                  int K, int N) {
    __shared__ float tile[32][33];
    int n0 = blockIdx.x * 32, k0 = blockIdx.y * 32;
    int tx = threadIdx.x, ty = threadIdx.y;   // 32 x 8
#pragma unroll
    for (int j = 0; j < 4; j++)
        tile[ty + j * 8][tx] = W[(size_t)(k0 + ty + j * 8) * N + n0 + tx];
    __syncthreads();
#pragma unroll
    for (int j = 0; j < 4; j++)
        WT[(size_t)(n0 + ty + j * 8) * K + k0 + tx] = __float2bfloat16(tile[tx][ty + j * 8]);
}

// ---------------- bf16 transpose for V: qkv v-section -> vbT [B][512][1024] ----------------
__global__ void transpose_v(const __hip_bfloat16* __restrict__ qkv, __hip_bfloat16* __restrict__ vbT) {
    __shared__ __hip_bfloat16 tile[32][33];
    int c0 = blockIdx.x * 32;   // v col 0..511
    int s0 = blockIdx.y * 32;   // seq within batch
    int b = blockIdx.z;
    int tx = threadIdx.x, ty = threadIdx.y;   // 32 x 8
#pragma unroll
    for (int j = 0; j < 4; j++)
        tile[ty + j * 8][tx] = qkv[(size_t)(b * T_SEQ + s0 + ty + j * 8) * NTOT + DMODEL + KVDIM + c0 + tx];
    __syncthreads();
#pragma unroll
    for (int j = 0; j < 4; j++)
        vbT[((size_t)b * KVDIM + c0 + ty + j * 8) * T_SEQ + s0 + tx] = tile[tx][ty + j * 8];
}

// ---------------- RoPE in-place on q,k sections of qkv (bf16) ----------------
__global__ void rope_kernel(__hip_bfloat16* __restrict__ qkv, const int* __restrict__ pos_ids) {
    int row = blockIdx.x;              // 0..2047
    int tid = threadIdx.x;             // 256
    float fpos = (float)pos_ids[row];
    __hip_bfloat16* rp = qkv + (size_t)row * NTOT;
    for (int p = tid; p < 32 * 64; p += 256) {
        int hh = p >> 6;               // 0..31 (28 q heads + 4 k heads)
        int j = p & 63;
        int cb = (hh < NQH) ? hh * HD : DMODEL + (hh - NQH) * HD;
        float ts = powf(1000000.0f, (float)j * (1.0f / 64.0f));
        float ang = fpos / ts;
        float s = sinf(ang), c = cosf(ang);
        float x1 = __bfloat162float(rp[cb + j]);
        float x2 = __bfloat162float(rp[cb + j + 64]);
        rp[cb + j] = __float2bfloat16(x1 * c - x2 * s);
        rp[cb + j + 64] = __float2bfloat16(x2 * c + x1 * s);
    }
}

// ---------------- m97-structure bf16 GEMM: C = A * BT^T (+bias) ----------------
// A: MxK bf16 row-major; BT: NxK bf16 row-major. Tiles 128x128x32, 4 waves.
// MODE 0: bf16 out with qkv bias split; MODE 1: fp32 out, no bias.
template <int MODE>
__global__ __launch_bounds__(256, 2) void gemm_bt(
    const __hip_bfloat16* __restrict__ A, const __hip_bfloat16* __restrict__ BT,
    int M, int N, int K,
    const float* __restrict__ bq, const float* __restrict__ bk, const float* __restrict__ bv,
    __hip_bfloat16* __restrict__ Cb, float* __restrict__ Cf) {
    __shared__ __hip_bfloat16 As[128 * 32];
    __shared__ __hip_bfloat16 Bs[128 * 32];
    int tid = threadIdx.x;
    int w = tid >> 6, lane = tid & 63;
    int wr = w >> 1, wc = w & 1;
    int bm = blockIdx.y * 128, bn = blockIdx.x * 128;
    int r16 = lane & 15, g4 = lane >> 4;
    int lrow = lane >> 2;          // 0..15 within a 16-row chunk
    int lk = (lane & 3) * 8;       // k element offset within 32
    int c0 = w * 2, c1 = w * 2 + 1;

    const __hip_bfloat16* Ag0 = A + (size_t)(bm + c0 * 16 + lrow) * K + lk;
    const __hip_bfloat16* Ag1 = A + (size_t)(bm + c1 * 16 + lrow) * K + lk;
    const __hip_bfloat16* Bg0 = BT + (size_t)(bn + c0 * 16 + lrow) * K + lk;
    const __hip_bfloat16* Bg1 = BT + (size_t)(bn + c1 * 16 + lrow) * K + lk;
    __hip_bfloat16* Al0 = As + c0 * 512;
    __hip_bfloat16* Al1 = As + c1 * 512;
    __hip_bfloat16* Bl0 = Bs + c0 * 512;
    __hip_bfloat16* Bl1 = Bs + c1 * 512;

    f32x4 acc[4][4] = {};
    for (int kt = 0; kt < K; kt += 32) {
        gload_lds16(Ag0 + kt, Al0);
        gload_lds16(Ag1 + kt, Al1);
        gload_lds16(Bg0 + kt, Bl0);
        gload_lds16(Bg1 + kt, Bl1);
        __syncthreads();
        short8 aF[4], bF[4];
#pragma unroll
        for (int m = 0; m < 4; m++)
            aF[m] = *reinterpret_cast<const short8*>(As + (wr * 64 + m * 16 + r16) * 32 + g4 * 8);
#pragma unroll
        for (int n = 0; n < 4; n++)
            bF[n] = *reinterpret_cast<const short8*>(Bs + (wc * 64 + n * 16 + r16) * 32 + g4 * 8);
#pragma unroll
        for (int m = 0; m < 4; m++)
#pragma unroll
            for (int n = 0; n < 4; n++)
                acc[m][n] = mfma16(aF[m], bF[n], acc[m][n]);
        __syncthreads();
    }
    // epilogue: C/D layout col=lane&15, row=(lane>>4)*4+reg
#pragma unroll
    for (int m = 0; m < 4; m++) {
#pragma unroll
        for (int n = 0; n < 4; n++) {
            int row0 = bm + wr * 64 + m * 16 + g4 * 4;
            int col = bn + wc * 64 + n * 16 + r16;
            float badd = 0.0f;
            if (MODE == 0)
                badd = (col < DMODEL) ? bq[col]
                       : (col < DMODEL + KVDIM ? bk[col - DMODEL] : bv[col - DMODEL - KVDIM]);
#pragma unroll
            for (int reg = 0; reg < 4; reg++) {
                float v = acc[m][n][reg] + badd;
                if (MODE == 0)
                    Cb[(size_t)(row0 + reg) * N + col] = __float2bfloat16(v);
                else
                    Cf[(size_t)(row0 + reg) * N + col] = v;
            }
        }
    }
}

// ---------------- flash attention: 1 wave/block, 16 q-rows, KV step 32 ----------------
__global__ __launch_bounds__(64, 2) void attn_kernel(
    const __hip_bfloat16* __restrict__ qkv, const __hip_bfloat16* __restrict__ vbT,
    const int* __restrict__ seg, const int* __restrict__ left_pads,
    __hip_bfloat16* __restrict__ attn_out) {
    int qt = blockIdx.x;   // 0..63 (16-row q tiles)
    int h = blockIdx.y;    // 0..27
    int b = blockIdx.z;
    int kvh = h / NREP;
    int lane = threadIdx.x;
    int r = lane & 15, g = lane >> 4;
    int start = left_pads[b];
    const float scale = 0.08838834764831845f;

    __shared__ __hip_bfloat16 Ps[16][40];   // 40-pad: 16B-aligned rows, conflict-friendly

    // Q fragments: A layout row=lane&15, k=(lane>>4)*8+j (contiguous 8)
    const __hip_bfloat16* Qp = qkv + (size_t)(b * T_SEQ + qt * 16 + r) * NTOT + h * HD;
    short8 qf[4];
#pragma unroll
    for (int kc = 0; kc < 4; kc++) qf[kc] = ld_s8(Qp + kc * 32 + g * 8);

    // per-lane row metadata for rows g*4+reg
    int qpos[4], segq[4];
#pragma unroll
    for (int reg = 0; reg < 4; reg++) {
        int trow = qt * 16 + g * 4 + reg;
        segq[reg] = seg[b * T_SEQ + trow];
        qpos[reg] = trow - start;
    }
    float m_run[4], l_run[4];
#pragma unroll
    for (int reg = 0; reg < 4; reg++) { m_run[reg] = -__builtin_inff(); l_run[reg] = 0.0f; }
    f32x4 acc[8] = {};

    const __hip_bfloat16* Kbase = qkv + (size_t)(b * T_SEQ) * NTOT + DMODEL + kvh * HD;
    const __hip_bfloat16* Vbase = vbT + ((size_t)b * KVDIM + kvh * HD) * T_SEQ;
    int smax = qt * 16 + 15;

    for (int s0 = 0; s0 <= smax; s0 += 32) {
        // QK^T for 32 kv cols
        f32x4 sacc[2] = {};
#pragma unroll
        for (int n = 0; n < 2; n++) {
            const __hip_bfloat16* Kp = Kbase + (size_t)(s0 + n * 16 + r) * NTOT;
#pragma unroll
            for (int kc = 0; kc < 4; kc++) {
                short8 kf = ld_s8(Kp + kc * 32 + g * 8);
                sacc[n] = mfma16(qf[kc], kf, sacc[n]);
            }
        }
        // mask + per-row tile max
        float pmat[2][4], mt[4];
#pragma unroll
        for (int reg = 0; reg < 4; reg++) mt[reg] = -__builtin_inff();
#pragma unroll
        for (int n = 0; n < 2; n++) {
            int sidx = s0 + n * 16 + r;
            int kpos = sidx - start;
            int kseg = (sidx >= start) ? 1 : 0;
#pragma unroll
            for (int reg = 0; reg < 4; reg++) {
                float val = sacc[n][reg] * scale;
                bool ok = (kpos <= qpos[reg]) && (kseg == segq[reg]);
                val = ok ? val : KMASK;
                pmat[n][reg] = val;
                mt[reg] = fmaxf(mt[reg], val);
            }
        }
#pragma unroll
        for (int off = 8; off >= 1; off >>= 1)
#pragma unroll
            for (int reg = 0; reg < 4; reg++)
                mt[reg] = fmaxf(mt[reg], __shfl_xor(mt[reg], off, 64));
        // online softmax update
        float fac[4], rs[4];
#pragma unroll
        for (int reg = 0; reg < 4; reg++) {
            float mn = fmaxf(m_run[reg], mt[reg]);
            fac[reg] = __expf(m_run[reg] - mn);
            float p0 = __expf(pmat[0][reg] - mn);
            float p1 = __expf(pmat[1][reg] - mn);
            pmat[0][reg] = p0; pmat[1][reg] = p1;
            rs[reg] = p0 + p1;
            m_run[reg] = mn;
        }
#pragma unroll
        for (int off = 1; off < 16; off <<= 1)
#pragma unroll
            for (int reg = 0; reg < 4; reg++)
                rs[reg] += __shfl_xor(rs[reg], off, 64);
#pragma unroll
        for (int reg = 0; reg < 4; reg++)
            l_run[reg] = l_run[reg] * fac[reg] + rs[reg];
        // P -> LDS transpose (cross-lane), then PV
        __syncthreads();   // WAR: prior iteration reads done
#pragma unroll
        for (int n = 0; n < 2; n++)
#pragma unroll
            for (int reg = 0; reg < 4; reg++)
                Ps[g * 4 + reg][n * 16 + r] = __float2bfloat16(pmat[n][reg]);
        __syncthreads();   // make writes visible within the wave
        short8 a_pv = *reinterpret_cast<const short8*>(&Ps[r][g * 8]);
        // rescale accumulator
#pragma unroll
        for (int h7 = 0; h7 < 8; h7++)
#pragma unroll
            for (int reg = 0; reg < 4; reg++)
                acc[h7][reg] *= fac[reg];
#pragma unroll
        for (int h7 = 0; h7 < 8; h7++) {
            short8 vf = ld_s8(Vbase + (size_t)(h7 * 16 + r) * T_SEQ + s0 + g * 8);
            acc[h7] = mfma16(a_pv, vf, acc[h7]);
        }
    }
    // normalize + write bf16 [2048][3584]
    float invl[4];
#pragma unroll
    for (int reg = 0; reg < 4; reg++) invl[reg] = 1.0f / l_run[reg];
#pragma unroll
    for (int h7 = 0; h7 < 8; h7++)
#pragma unroll
        for (int reg = 0; reg < 4; reg++)
            attn_out[(size_t)(b * T_SEQ + qt * 16 + g * 4 + reg) * DMODEL + h * HD + h7 * 16 + r] =
                __float2bfloat16(acc[h7][reg] * invl[reg]);
}

extern "C" void kernel_launch(void* const* d_in, const int* in_sizes, int n_in,
                              void* d_out, int out_size, void* d_ws, size_t ws_size,
                              hipStream_t stream) {
    const float* x = (const float*)d_in[0];
    const int* seg = (const int*)d_in[1];
    const float* Wq = (const float*)d_in[4];
    const float* bq = (const float*)d_in[5];
    const float* Wk = (const float*)d_in[6];
    const float* bk = (const float*)d_in[7];
    const float* Wv = (const float*)d_in[8];
    const float* bv = (const float*)d_in[9];
    const float* Wo = (const float*)d_in[10];
    float* out = (float*)d_out;

    uint8_t* ws = (uint8_t*)d_ws;
    size_t off = 0;
    auto alloc = [&](size_t bytes) -> void* {
        void* p = ws + off;
        off += (bytes + 255) & ~(size_t)255;
        return p;
    };
    int* pos_ids = (int*)alloc(MROWS * sizeof(int));
    int* left_pads = (int*)alloc(16 * sizeof(int));
    __hip_bfloat16* xb = (__hip_bfloat16*)alloc((size_t)MROWS * DMODEL * 2);
    __hip_bfloat16* WqkvT = (__hip_bfloat16*)alloc((size_t)NTOT * DMODEL * 2);
    __hip_bfloat16* WoT = (__hip_bfloat16*)alloc((size_t)DMODEL * DMODEL * 2);
    __hip_bfloat16* qkv = (__hip_bfloat16*)alloc((size_t)MROWS * NTOT * 2);
    __hip_bfloat16* vbT = (__hip_bfloat16*)alloc((size_t)BATCH * KVDIM * T_SEQ * 2);
    __hip_bfloat16* attn = (__hip_bfloat16*)alloc((size_t)MROWS * DMODEL * 2);

    scan_kernel<<<BATCH, T_SEQ, 0, stream>>>(seg, pos_ids, left_pads);
    convert_bf16<<<(MROWS * DMODEL / 4 + 255) / 256, 256, 0, stream>>>(x, xb, MROWS * DMODEL);
    transpose_convert<<<dim3(DMODEL / 32, DMODEL / 32), dim3(32, 8), 0, stream>>>(Wq, WqkvT, DMODEL, DMODEL);
    transpose_convert<<<dim3(KVDIM / 32, DMODEL / 32), dim3(32, 8), 0, stream>>>(
        Wk, WqkvT + (size_t)DMODEL * DMODEL, DMODEL, KVDIM);
    transpose_convert<<<dim3(KVDIM / 32, DMODEL / 32), dim3(32, 8), 0, stream>>>(
        Wv, WqkvT + (size_t)(DMODEL + KVDIM) * DMODEL, DMODEL, KVDIM);
    transpose_convert<<<dim3(DMODEL / 32, DMODEL / 32), dim3(32, 8), 0, stream>>>(Wo, WoT, DMODEL, DMODEL);
    gemm_bt<0><<<dim3(NTOT / 128, MROWS / 128), 256, 0, stream>>>(
        xb, WqkvT, MROWS, NTOT, DMODEL, bq, bk, bv, qkv, nullptr);
    rope_kernel<<<MROWS, 256, 0, stream>>>(qkv, pos_ids);
    transpose_v<<<dim3(KVDIM / 32, T_SEQ / 32, BATCH), dim3(32, 8), 0, stream>>>(qkv, vbT);
    attn_kernel<<<dim3(T_SEQ / 16, NQH, BATCH), 64, 0, stream>>>(qkv, vbT, seg, left_pads, attn);
    gemm_bt<1><<<dim3(DMODEL / 128, MROWS / 128), 256, 0, stream>>>(
        attn, WoT, MROWS, DMODEL, DMODEL, nullptr, nullptr, nullptr, nullptr, out);
}